// Round 1
// baseline (52.049 us; speedup 1.0000x reference)
//
#include <hip/hip_runtime.h>
#include <hip/hip_bf16.h>
#include <stdint.h>

#define NN 1024
#define EMBED 256
#define NHEAD 8
#define NHID 32
#define SLOPE 0.2f

// ---------------- edge -> adjacency bitmask (dedupes duplicates) -------------
__global__ void k_edges(const int* __restrict__ ei, unsigned long long* __restrict__ adj, int E) {
    int e = blockIdx.x * blockDim.x + threadIdx.x;
    if (e < E) {
        int r = ei[2 * e];      // destination i
        int c = ei[2 * e + 1];  // source j
        atomicOr(&adj[r * 16 + (c >> 6)], 1ull << (c & 63));
    }
}

// ---------------- g_l = h@W_l, g_r = h@W_r (selected by blockIdx.z) ----------
// BM=64, BN=64, BK=16, 256 threads, 4x4 micro-tile per thread.
__global__ __launch_bounds__(256) void k_gemm(const float* __restrict__ h,
                                              const float* __restrict__ Wl,
                                              const float* __restrict__ Wr,
                                              float* __restrict__ gl,
                                              float* __restrict__ gr) {
    const float* W = blockIdx.z ? Wr : Wl;
    float* out = blockIdx.z ? gr : gl;
    const int bm = blockIdx.y * 64;
    const int bn = blockIdx.x * 64;
    const int t = threadIdx.x;
    const int tx = t & 15;       // 0..15 -> 4 cols each
    const int ty = t >> 4;       // 0..15 -> 4 rows each

    __shared__ float As[16][65];   // [k][m]
    __shared__ float Bs[16][65];   // [k][n]

    float acc[4][4];
#pragma unroll
    for (int i = 0; i < 4; ++i)
#pragma unroll
        for (int j = 0; j < 4; ++j) acc[i][j] = 0.f;

    for (int k0 = 0; k0 < EMBED; k0 += 16) {
        // A tile: 64 rows x 16 k. thread loads float4: row = t/4, k = (t%4)*4
        {
            int r = t >> 2;
            int c = (t & 3) << 2;
            float4 v = *reinterpret_cast<const float4*>(&h[(bm + r) * EMBED + k0 + c]);
            As[c + 0][r] = v.x;
            As[c + 1][r] = v.y;
            As[c + 2][r] = v.z;
            As[c + 3][r] = v.w;
        }
        // B tile: 16 k x 64 cols. thread loads float4: k = t/16, col = (t%16)*4
        {
            int r = t >> 4;
            int c = (t & 15) << 2;
            float4 v = *reinterpret_cast<const float4*>(&W[(k0 + r) * EMBED + bn + c]);
            Bs[r][c + 0] = v.x;
            Bs[r][c + 1] = v.y;
            Bs[r][c + 2] = v.z;
            Bs[r][c + 3] = v.w;
        }
        __syncthreads();
#pragma unroll
        for (int kk = 0; kk < 16; ++kk) {
            float a[4], b[4];
#pragma unroll
            for (int i = 0; i < 4; ++i) a[i] = As[kk][ty * 4 + i];
#pragma unroll
            for (int j = 0; j < 4; ++j) b[j] = Bs[kk][tx * 4 + j];
#pragma unroll
            for (int i = 0; i < 4; ++i)
#pragma unroll
                for (int j = 0; j < 4; ++j) acc[i][j] += a[i] * b[j];
        }
        __syncthreads();
    }

#pragma unroll
    for (int i = 0; i < 4; ++i) {
        float4 v = make_float4(acc[i][0], acc[i][1], acc[i][2], acc[i][3]);
        *reinterpret_cast<float4*>(&out[(bm + ty * 4 + i) * EMBED + bn + tx * 4]) = v;
    }
}

// ---------------- per-destination-row sparse softmax + aggregate -------------
// One block (256 threads) per destination row i. Thread t owns output feature
// f = t  (head h = t/32, dim d = t%32). All threads walk the same (uniform)
// edge list from the adjacency bits; scores reduce within each 32-lane group.
__global__ __launch_bounds__(256) void k_attn(const float* __restrict__ gl,
                                              const float* __restrict__ gr,
                                              const unsigned long long* __restrict__ adj,
                                              const float* __restrict__ attn_w,
                                              float* __restrict__ out) {
    const int i = blockIdx.x;
    const int t = threadIdx.x;

    const float grv = gr[i * EMBED + t];
    const float aw = attn_w[t & 31];

    float m = -INFINITY;
    float s = 0.f;
    float acc = 0.f;

    for (int w = 0; w < 16; ++w) {
        unsigned long long bits = adj[i * 16 + w];
        while (bits) {
            int b = __builtin_ctzll(bits);
            bits &= bits - 1;
            int j = w * 64 + b;
            float glv = gl[j * EMBED + t];
            float x = glv + grv;
            float p = (x > 0.f ? x : SLOPE * x) * aw;
            // sum over d (32 lanes of this head's group)
            p += __shfl_xor(p, 1);
            p += __shfl_xor(p, 2);
            p += __shfl_xor(p, 4);
            p += __shfl_xor(p, 8);
            p += __shfl_xor(p, 16);
            // online softmax update
            float mn = fmaxf(m, p);
            float sc = __expf(m - mn);
            float ev = __expf(p - mn);
            s = s * sc + ev;
            acc = acc * sc + ev * glv;
            m = mn;
        }
    }
    out[i * EMBED + t] = acc / s;
}

extern "C" void kernel_launch(void* const* d_in, const int* in_sizes, int n_in,
                              void* d_out, int out_size, void* d_ws, size_t ws_size,
                              hipStream_t stream) {
    const float* h  = (const float*)d_in[0];
    const int*   ei = (const int*)d_in[1];
    const float* Wl = (const float*)d_in[2];
    const float* Wr = (const float*)d_in[3];
    const float* aw = (const float*)d_in[4];
    float* out = (float*)d_out;
    const int E = in_sizes[1] / 2;

    unsigned long long* adj = (unsigned long long*)d_ws;                 // 128 KB
    float* gl = (float*)((char*)d_ws + 131072);                          // 1 MB
    float* gr = gl + NN * EMBED;                                         // 1 MB

    hipMemsetAsync(d_ws, 0, 131072, stream);
    k_edges<<<(E + 255) / 256, 256, 0, stream>>>(ei, adj, E);
    dim3 gg(EMBED / 64, NN / 64, 2);
    k_gemm<<<gg, 256, 0, stream>>>(h, Wl, Wr, gl, gr);
    k_attn<<<NN, 256, 0, stream>>>(gl, gr, adj, aw, out);
}